// Round 15
// baseline (205.332 us; speedup 1.0000x reference)
//
#include <hip/hip_runtime.h>
#include <stdint.h>

#define NCLS 80
#define MAXB 150
#define BATCH 16
#define NANCH 25200
#define SEGS 4       // candidate-list segments per (image,class) (atomic spread)
#define SEGCAP 512   // per-segment cap; mean fill ~150 -> ~10 sigma margin
#define CAP2 12000   // hard bound: 80 classes * 150 kept max
#define NBINS 411    // score hi-bits (0x3F666666,0x3F800000] -> bins 0..410
#define SELCAP 2048
#define WSEL 256     // nms per-wave compact capacity (expected ~155)
#define NREC_ALL 403200  // total records across levels/images
#define CPAD 16          // counters padded to one per 64B line (atomic contention fix)

typedef unsigned long long u64;
typedef unsigned int u32;
typedef float f4 __attribute__((ext_vector_type(4)));
typedef f4 f4u __attribute__((aligned(4)));  // 4B-aligned vector load

__device__ __forceinline__ float sigm(float x) { return 1.0f / (1.0f + expf(-x)); }

// reference IoU, exact op order: inter / ((area_row + area_col) - inter + 1e-9)
__device__ __forceinline__ float iou_ref(float4 rb_, float ra, float4 cb, float ca) {
  float ltx = fmaxf(rb_.x, cb.x);
  float lty = fmaxf(rb_.y, cb.y);
  float rbx = fminf(rb_.z, cb.z);
  float rby = fminf(rb_.w, cb.w);
  float iw = fmaxf(rbx - ltx, 0.f);
  float ih = fmaxf(rby - lty, 0.f);
  float inter = iw * ih;
  return inter / (ra + ca - inter + 1e-9f);
}

// -- Pass 1a: headers -> hot-record compaction (+ boxes/thr/cs for hot only) ----
// Hot = cs>0.9 (19%). Cold records get NO box write, NO thr entry: keys only
// ever reference hot anchors, so cold boxes are never read downstream.
__global__ __launch_bounds__(256) void header_kernel(
    const float* __restrict__ p0, const float* __restrict__ p1,
    const float* __restrict__ p2, float* __restrict__ boxes_ws,
    u32* __restrict__ hot_W, float* __restrict__ hot_thr,
    float* __restrict__ hot_cs, int* __restrict__ hotcnt) {
  int W = blockIdx.x * 256 + threadIdx.x;  // 0..403199, level-major record id
  int lvl, b, r;
  if (W < 19200) { lvl = 0; b = W / 1200; r = W - b * 1200; }
  else if (W < 96000) { int V = W - 19200; lvl = 1; b = V / 4800; r = V - b * 4800; }
  else { int V = W - 96000; lvl = 2; b = V / 19200; r = V - b * 19200; }
  const int gtab[3] = {20, 40, 80};
  const float rtab[3] = {32.f, 16.f, 8.f};
  const int nbt[3] = {0, 1200, 6000};
  const float awt[3][3] = {{116.f, 156.f, 373.f}, {30.f, 62.f, 59.f}, {10.f, 16.f, 33.f}};
  const float aht[3][3] = {{90.f, 198.f, 326.f}, {61.f, 45.f, 119.f}, {13.f, 30.f, 23.f}};
  const float* fm = (lvl == 0) ? p0 : ((lvl == 1) ? p1 : p2);
  int g = gtab[lvl];
  const float* p = fm + ((size_t)b * (g * g * 3) + r) * 85;
  float tc = p[4];
  float cs = sigm(tc);  // score<=cs in fp32 -> cs>0.9 is a lossless gate
  bool hot = cs > 0.9f;
  float thr = 0.f;
  if (hot) {
    f4 h = *(const f4u*)p;  // tx,ty,tw,th
    int cell = r / 3, a = r - 3 * cell;
    int yy = cell / g, xx = cell - yy * g;
    float ratio = rtab[lvl];
    float cx = (sigm(h.x) + (float)xx) * ratio;
    float cy = (sigm(h.y) + (float)yy) * ratio;
    float w = expf(h.z) * awt[lvl][a];
    float hh = expf(h.w) * aht[lvl][a];
    int n = nbt[lvl] + r;
    reinterpret_cast<float4*>(boxes_ws)[(size_t)b * NANCH + n] = make_float4(
        cx - w * 0.5f, cy - hh * 0.5f, cx + w * 0.5f, cy + hh * 0.5f);
    // conservative logit threshold: val <= thr ==> fl(cs*sigm(val)) <= 0.9f;
    // margin dominates all fp32 error terms; borderline FPs re-tested exactly.
    float t = 0.9f / cs;
    float ratio2 = t / (1.0f - t);
    thr = logf(ratio2) - (1e-3f + 4e-7f * ratio2);
  }
  // wave-aggregated append to the dense hot list (one atomic per wave)
  u64 mask = __ballot(hot);
  if (mask) {
    int lane = threadIdx.x & 63;
    u64 ltm = (1ull << lane) - 1;
    int leader = __ffsll(mask) - 1;
    int base = 0;
    if (lane == leader) base = atomicAdd(hotcnt, (int)__popcll(mask));
    base = __shfl(base, leader);
    if (hot) {
      int pos = base + (int)__popcll(mask & ltm);
      hot_W[pos] = (u32)W;
      hot_thr[pos] = thr;
      hot_cs[pos] = cs;
    }
  }
}

// -- Pass 1b: dense class gather: thread per (hot record, class-float4 slot) ----
// Every working wave is 100% hot; 20 consecutive threads read one 320B row.
__global__ __launch_bounds__(256) void class_kernel(
    const float* __restrict__ p0, const float* __restrict__ p1,
    const float* __restrict__ p2, const u32* __restrict__ hot_W,
    const float* __restrict__ hot_thr, const float* __restrict__ hot_cs,
    const int* __restrict__ hotcnt,
    u64* __restrict__ cand_keys, int* __restrict__ cand_cnt) {
  u32 gid = blockIdx.x * 256u + threadIdx.x;
  u32 H = (u32)*hotcnt;                  // broadcast counter read
  u32 i = gid / 20u, slot = gid - i * 20u;
  if (i >= H) return;                    // dead tail exits cheaply
  u32 W = hot_W[i];                      // dense sequential reads
  float thr = hot_thr[i];
  int lvl, b, r;
  const float* fm;
  if (W < 19200u) { lvl = 0; b = W / 1200u; r = W - b * 1200u; fm = p0; }
  else if (W < 96000u) { u32 V = W - 19200u; lvl = 1; b = V / 4800u; r = V - b * 4800u; fm = p1; }
  else { u32 V = W - 96000u; lvl = 2; b = V / 19200u; r = V - b * 19200u; fm = p2; }
  const int lbase[3] = {0, 19200, 96000};
  const int nbt[3] = {0, 1200, 6000};
  const float* p = fm + (size_t)(W - (u32)lbase[lvl]) * 85;
  f4 v = *(const f4u*)(p + 5 + 4 * slot);  // 16B of class logits (4B-aligned)
  u32 n = (u32)nbt[lvl] + (u32)r;
  u32 nkey = 0xFFFFFFFFu - n;
  int seg = (int)(W & (SEGS - 1));
#pragma unroll
  for (int k = 0; k < 4; ++k) {
    if (v[k] > thr) {  // lossless pre-filter (thr conservative)
      float cs = hot_cs[i];
      float s = cs * sigm(v[k]);  // exact reference expression
      if (s > 0.9f) {
        int c = 4 * (int)slot + k;
        int bc = b * NCLS + c;
        int pos = atomicAdd(&cand_cnt[(bc * SEGS + seg) * CPAD], 1);
        if (pos < SEGCAP)  // high = score bits, low = ~anchor (desc => idx-asc ties)
          cand_keys[((size_t)bc * SEGS + seg) * SEGCAP + pos] =
              ((u64)__float_as_uint(s) << 32) | nkey;
      }
    }
  }
}

// ------- Pass 2: one WAVE per (image,class): select top-150 + bitmask NMS -------
// Zero __syncthreads; serial NMS scan is register-only (no cross-lane ops).
__global__ __launch_bounds__(64) void nms_kernel(
    const u64* __restrict__ cand_keys, const int* __restrict__ cand_cnt,
    const float* __restrict__ boxes_ws,
    u64* __restrict__ img_keys, int* __restrict__ img_cnt) {
  __shared__ u64 sk[SEGS * SEGCAP];  // 16 KB staged keys
  __shared__ u64 sel[WSEL + 8];      // compact buffer (+pad)
  __shared__ u64 slot[MAXB];         // top-150 keys by exact rank
  __shared__ float4 sbox[MAXB];
  __shared__ float sarea[MAXB];
  __shared__ u64 adjm[MAXB][3];      // adjacency rows: 192-bit masks
  __shared__ u32 hist[NBINS];
  int bc = blockIdx.x;
  int b = bc / NCLS, c = bc - b * NCLS;
  int lane = threadIdx.x;
  u64 ltm = (1ull << lane) - 1;
  int cnt[SEGS];
  int count = 0;
#pragma unroll
  for (int s = 0; s < SEGS; ++s) {
    int v = cand_cnt[(bc * SEGS + s) * CPAD];
    cnt[s] = (v > SEGCAP) ? SEGCAP : v;
    count += cnt[s];
  }
  const u64* seg_base = cand_keys + (size_t)bc * SEGS * SEGCAP;
  for (int i = lane; i < NBINS; i += 64) hist[i] = 0;
  for (int i = lane; i < MAXB; i += 64) slot[i] = 0;
  // ---- stage keys to LDS + histogram in ONE pass ----
  {
    int off = 0;
#pragma unroll
    for (int s = 0; s < SEGS; ++s) {
      for (int i = lane; i < cnt[s]; i += 64) {
        u64 k = seg_base[s * SEGCAP + i];
        sk[off + i] = k;
        atomicAdd(&hist[((u32)(k >> 32) - 0x3F666000u) >> 12], 1u);
      }
      off += cnt[s];
    }
  }
  __threadfence_block();
  // ---- wave-parallel suffix-scan threshold: lane owns 7-bin chunk ----
  int target = (count < MAXB) ? count : MAXB;
  u32 bsum[7];
  u32 csum = 0;
  int chunk = lane * 7;  // 64*7 = 448 >= NBINS
#pragma unroll
  for (int m = 0; m < 7; ++m) {
    int j = chunk + m;
    u32 hv = (j < NBINS) ? hist[j] : 0u;
    bsum[m] = hv;
    csum += hv;
  }
  u32 S = csum;  // inclusive suffix sum over lanes
#pragma unroll
  for (int off = 1; off < 64; off <<= 1) {
    u32 o = __shfl_down(S, off);
    if (lane + off < 64) S += o;
  }
  u32 Snext = S - csum;
  bool win = (S >= (u32)target) && (Snext < (u32)target);  // unique lane (target>=1)
  u64 wmask = __ballot(win);
  int T = NBINS;
  u32 Cge = 0;
  if (wmask) {
    int Tc = 0;
    u32 Cc = 0;
    if (win) {
      u32 acc = Snext;
#pragma unroll
      for (int m = 6; m >= 0; --m) {
        acc += bsum[m];
        if (acc >= (u32)target) { Tc = chunk + m; Cc = acc; break; }
      }
    }
    int wl = __ffsll(wmask) - 1;
    T = __shfl(Tc, wl);
    Cge = __shfl(Cc, wl);
  }
  // ---- select top-`target` keys into slot[rank] ----
  if (Cge <= WSEL) {
    int C = 0;  // compact bins >= T via ballot offsets; C == Cge
    for (int i0 = 0; i0 < count; i0 += 64) {
      int i = i0 + lane;
      bool in = false;
      u64 k = 0;
      if (i < count) {
        k = sk[i];
        in = (int)(((u32)(k >> 32) - 0x3F666000u) >> 12) >= T;
      }
      u64 m = __ballot(in);
      if (in) sel[C + (int)__popcll(m & ltm)] = k;
      C += (int)__popcll(m);
    }
    int C8 = (C + 7) & ~7;
    for (int j = C + lane; j < C8; j += 64) sel[j] = 0;  // pad: 0 never outranks
    __threadfence_block();
    for (int i = lane; i < C; i += 64) {  // rank-select, broadcast reads, 8-deep
      u64 k = sel[i];
      int rank = 0;
      for (int j = 0; j < C8; j += 8) {
        rank += (int)(sel[j] > k) + (int)(sel[j + 1] > k) + (int)(sel[j + 2] > k) +
                (int)(sel[j + 3] > k) + (int)(sel[j + 4] > k) + (int)(sel[j + 5] > k) +
                (int)(sel[j + 6] > k) + (int)(sel[j + 7] > k);
      }
      if (rank < MAXB) slot[rank] = k;
    }
  } else {
    // fallback (pathological bin concentration; never taken on this data)
    int C8 = (count + 7) & ~7;  // <= 2048 (sk capacity)
    for (int j = count + lane; j < C8; j += 64) sk[j] = 0;
    __threadfence_block();
    for (int i = lane; i < count; i += 64) {
      u64 k = sk[i];
      int rank = 0;
      for (int j = 0; j < C8; j += 8) {
        rank += (int)(sk[j] > k) + (int)(sk[j + 1] > k) + (int)(sk[j + 2] > k) +
                (int)(sk[j + 3] > k) + (int)(sk[j + 4] > k) + (int)(sk[j + 5] > k) +
                (int)(sk[j + 6] > k) + (int)(sk[j + 7] > k);
      }
      if (rank < MAXB) slot[rank] = k;
    }
  }
  __threadfence_block();
  // ---- boxes: registers for my 3 rows + LDS copy for broadcast columns ----
  float4 rb0, rb1, rb2;
  float ra0 = 0.f, ra1 = 0.f, ra2 = 0.f;
  rb0 = rb1 = rb2 = make_float4(0.f, 0.f, 0.f, 0.f);
#pragma unroll
  for (int w = 0; w < 3; ++w) {
    int j = lane + 64 * w;
    float4 bx = make_float4(0.f, 0.f, 0.f, 0.f);
    float ar = 0.f;
    if (j < MAXB && slot[j] != 0) {
      int n = (int)(0xFFFFFFFFu - (u32)(slot[j] & 0xFFFFFFFFu));
      bx = reinterpret_cast<const float4*>(boxes_ws)[(size_t)b * NANCH + n];
      ar = (bx.z - bx.x) * (bx.w - bx.y);
    }
    if (j < MAXB) { sbox[j] = bx; sarea[j] = ar; }
    if (w == 0) { rb0 = bx; ra0 = ar; }
    else if (w == 1) { rb1 = bx; ra1 = ar; }
    else { rb2 = bx; ra2 = ar; }
  }
  u64 valid0 = __ballot(slot[lane] != 0);
  u64 valid1 = __ballot(lane + 64 < MAXB && slot[lane + 64] != 0);
  u64 valid2 = __ballot(lane + 128 < MAXB && slot[lane + 128] != 0);
  __threadfence_block();
  // ---- adjacency build: row r mask = {bits j : j > r, iou(r,j) > 0.1} ----
  int jb0 = (target < 64) ? target : 64;
  int jb1 = (target < 128) ? target : 128;
  int jb2 = target;
  u64 r0m0 = 0, r0m1 = 0, r0m2 = 0, r1m1 = 0, r1m2 = 0, r2m2 = 0;
  bool rv0 = (valid0 >> lane) & 1, rv1 = (valid1 >> lane) & 1,
       rv2 = (valid2 >> lane) & 1;
  if (rv0) {
    u64 bit = 1ull;
    for (int j = 0; j < jb0; ++j, bit <<= 1)
      if (j > lane && iou_ref(rb0, ra0, sbox[j], sarea[j]) > 0.1f) r0m0 |= bit;
    bit = 1ull;
    for (int j = 64; j < jb1; ++j, bit <<= 1)
      if (iou_ref(rb0, ra0, sbox[j], sarea[j]) > 0.1f) r0m1 |= bit;
    bit = 1ull;
    for (int j = 128; j < jb2; ++j, bit <<= 1)
      if (iou_ref(rb0, ra0, sbox[j], sarea[j]) > 0.1f) r0m2 |= bit;
  }
  if (rv1) {
    u64 bit = 1ull;
    for (int j = 64; j < jb1; ++j, bit <<= 1)
      if (j > lane + 64 && iou_ref(rb1, ra1, sbox[j], sarea[j]) > 0.1f) r1m1 |= bit;
    bit = 1ull;
    for (int j = 128; j < jb2; ++j, bit <<= 1)
      if (iou_ref(rb1, ra1, sbox[j], sarea[j]) > 0.1f) r1m2 |= bit;
  }
  if (rv2) {
    u64 bit = 1ull;
    for (int j = 128; j < jb2; ++j, bit <<= 1)
      if (j > lane + 128 && iou_ref(rb2, ra2, sbox[j], sarea[j]) > 0.1f) r2m2 |= bit;
  }
  if (lane < MAXB) { adjm[lane][0] = r0m0; adjm[lane][1] = r0m1; adjm[lane][2] = r0m2; }
  if (lane + 64 < MAXB) { adjm[lane + 64][0] = 0; adjm[lane + 64][1] = r1m1; adjm[lane + 64][2] = r1m2; }
  if (lane + 128 < MAXB) { adjm[lane + 128][0] = 0; adjm[lane + 128][1] = 0; adjm[lane + 128][2] = r2m2; }
  __threadfence_block();
  // ---- serial greedy scan: register-only chain, identical in every lane ----
  u64 sup0 = 0, sup1 = 0, sup2 = 0;
  {
    u64 bit = 1ull;
    int e0 = (target < 64) ? target : 64;
    for (int i = 0; i < e0; ++i, bit <<= 1)
      if (valid0 & ~sup0 & bit) { sup0 |= adjm[i][0]; sup1 |= adjm[i][1]; sup2 |= adjm[i][2]; }
    bit = 1ull;
    int e1 = (target < 128) ? target - 64 : 64;
    for (int i = 0; i < e1; ++i, bit <<= 1)
      if (valid1 & ~sup1 & bit) { sup1 |= adjm[i + 64][1]; sup2 |= adjm[i + 64][2]; }
    bit = 1ull;
    int e2 = target - 128;
    for (int i = 0; i < e2; ++i, bit <<= 1)
      if (valid2 & ~sup2 & bit) { sup2 |= adjm[i + 128][2]; }
  }
  // ---- keep masks are uniform registers -> appends need no ballots ----
  u64 m0 = valid0 & ~sup0, m1 = valid1 & ~sup1, m2 = valid2 & ~sup2;
  int total = (int)(__popcll(m0) + __popcll(m1) + __popcll(m2));
  if (total > 0) {
    int base = 0;
    if (lane == 0) base = atomicAdd(&img_cnt[b * CPAD], total);
    base = __shfl(base, 0);
    int off0 = (int)__popcll(m0 & ltm);
    int off1 = (int)(__popcll(m0) + __popcll(m1 & ltm));
    int off2 = (int)(__popcll(m0) + __popcll(m1) + __popcll(m2 & ltm));
#pragma unroll
    for (int w = 0; w < 3; ++w) {
      u64 mw = (w == 0) ? m0 : ((w == 1) ? m1 : m2);
      if ((mw >> lane) & 1) {
        int j = lane + 64 * w;  // j == rank == top_k position
        u64 k = slot[j];
        u32 e = (u32)(c * MAXB + j);
        u32 anchor = (u32)(0xFFFFFFFFu - (u32)(k & 0xFFFFFFFFu));
        int pos = base + ((w == 0) ? off0 : ((w == 1) ? off1 : off2));
        // key = [score:32][(0x3FFF - e):14][anchor:15]  (unique per entry)
        img_keys[(size_t)b * CAP2 + pos] =
            ((k >> 32) << 32) | ((u64)(0x3FFFu - e) << 15) | anchor;
      }
    }
  }
}

// ---------------- Pass 3: per-image top-150 via exact histogram select ----------
__global__ __launch_bounds__(1024) void final_kernel(
    const u64* __restrict__ img_keys, const int* __restrict__ img_cnt,
    const float* __restrict__ boxes_ws, float* __restrict__ out) {
  __shared__ u32 hist[NBINS];
  __shared__ u64 sel[SELCAP];   // 16 KB
  __shared__ u64 slot[MAXB];
  __shared__ int sT, sCge, nsel;
  int b = blockIdx.x, tid = threadIdx.x;
  int L = img_cnt[b * CPAD];
  if (L > CAP2) L = CAP2;
  const u64* src = img_keys + (size_t)b * CAP2;
  for (int i = tid; i < NBINS; i += 1024) hist[i] = 0;
  if (tid < MAXB) slot[tid] = 0;
  if (tid == 0) nsel = 0;
  __syncthreads();
  for (int i = tid; i < L; i += 1024) {
    u32 hi = (u32)(src[i] >> 32);
    atomicAdd(&hist[(hi - 0x3F666000u) >> 12], 1u);
  }
  __syncthreads();
  if (tid < 64) {  // wave-parallel suffix-scan threshold
    int lane = tid;
    int target = (L < MAXB) ? L : MAXB;
    u32 bsum[7];
    u32 csum = 0;
    int chunk = lane * 7;
#pragma unroll
    for (int m = 0; m < 7; ++m) {
      int j = chunk + m;
      u32 hv = (j < NBINS) ? hist[j] : 0u;
      bsum[m] = hv;
      csum += hv;
    }
    u32 S = csum;
#pragma unroll
    for (int off = 1; off < 64; off <<= 1) {
      u32 o = __shfl_down(S, off);
      if (lane + off < 64) S += o;
    }
    u32 Snext = S - csum;
    bool win = (S >= (u32)target) && (Snext < (u32)target);
    u64 wmask = __ballot(win);
    int T = NBINS;
    u32 Cge = 0;
    if (wmask) {
      int Tc = 0;
      u32 Cc = 0;
      if (win) {
        u32 acc = Snext;
#pragma unroll
        for (int m = 6; m >= 0; --m) {
          acc += bsum[m];
          if (acc >= (u32)target) { Tc = chunk + m; Cc = acc; break; }
        }
      }
      int wl = __ffsll(wmask) - 1;
      T = __shfl(Tc, wl);
      Cge = __shfl(Cc, wl);
    }
    if (lane == 0) { sT = T; sCge = (int)Cge; }
  }
  __syncthreads();
  int T = sT, cge = sCge;
  float* ob = out;                      // [B][150][4]
  float* osc = out + BATCH * MAXB * 4;  // [B][150]
  float* olb = out + BATCH * MAXB * 5;  // [B][150] labels (as float)
  if (cge <= SELCAP) {
    for (int i = tid; i < L; i += 1024) {
      u64 k = src[i];
      if ((int)(((u32)(k >> 32) - 0x3F666000u) >> 12) >= T) {
        int pos = atomicAdd(&nsel, 1);
        sel[pos] = k;
      }
    }
    __syncthreads();
    int C = nsel;
    for (int i = tid; i < C; i += 1024) {
      u64 k = sel[i];
      int rank = 0;
      for (int j = 0; j < C; ++j) rank += (sel[j] > k) ? 1 : 0;  // LDS broadcast
      if (rank < MAXB) slot[rank] = k;
    }
    __syncthreads();
  } else {
    for (int i = tid; i < L; i += 1024) {
      u64 k = src[i];
      int rank = 0;
      for (int j = 0; j < L; ++j) rank += (src[j] > k) ? 1 : 0;
      if (rank < MAXB) slot[rank] = k;
    }
    __syncthreads();
  }
  if (tid < MAXB) {
    u64 k = slot[tid];
    float* q = ob + ((size_t)b * MAXB + tid) * 4;
    if (k) {
      u32 e = 0x3FFFu - (u32)((k >> 15) & 0x3FFFu);
      int c = (int)(e / MAXB);
      int anchor = (int)(k & 0x7FFFu);
      float4 bx = reinterpret_cast<const float4*>(boxes_ws)[(size_t)b * NANCH + anchor];
      q[0] = bx.x; q[1] = bx.y; q[2] = bx.z; q[3] = bx.w;
      osc[(size_t)b * MAXB + tid] = __uint_as_float((u32)(k >> 32));
      olb[(size_t)b * MAXB + tid] = (float)c;
    } else {
      q[0] = q[1] = q[2] = q[3] = -1.f;
      osc[(size_t)b * MAXB + tid] = -1.f;
      olb[(size_t)b * MAXB + tid] = -1.f;
    }
  }
}

extern "C" void kernel_launch(void* const* d_in, const int* in_sizes, int n_in,
                              void* d_out, int out_size, void* d_ws, size_t ws_size,
                              hipStream_t stream) {
  (void)in_sizes; (void)n_in; (void)out_size; (void)ws_size;
  const float* p0 = (const float*)d_in[0];  // [16,20,20,255] anchors[6:9]
  const float* p1 = (const float*)d_in[1];  // [16,40,40,255] anchors[3:6]
  const float* p2 = (const float*)d_in[2];  // [16,80,80,255] anchors[0:3]
  char* ws = (char*)d_ws;
  float* boxes_ws = (float*)ws;              // 16*25200*16 B          -> 6,451,200
  int* cand_cnt = (int*)(ws + 6451200);      // 1280*4*16 i32 (padded) -> 6,778,880
  int* img_cnt = (int*)(ws + 6778880);       // 16*16 i32 (padded)     -> 6,779,904
  int* hotcnt = (int*)(ws + 6779904);        // 16 i32 (one line)      -> 6,779,968
  u32* hot_W = (u32*)(ws + 6779968);         // 403200 u32             -> 8,392,768
  float* hot_thr = (float*)(ws + 8392768);   // 403200 f32             -> 10,005,568
  float* hot_cs = (float*)(ws + 10005568);   // 403200 f32             -> 11,618,368
  u64* cand_keys = (u64*)(ws + 11618368);    // 1280*4*512 u64         -> 32,589,888
  u64* img_keys = (u64*)(ws + 32589888);     // 16*12000 u64           -> 34,125,888

  // zero cand_cnt + img_cnt + hotcnt (contiguous padded counters)
  hipMemsetAsync(cand_cnt, 0,
                 (size_t)(NCLS * BATCH * SEGS + BATCH + 1) * CPAD * sizeof(int),
                 stream);

  header_kernel<<<NREC_ALL / 256, 256, 0, stream>>>(
      p0, p1, p2, boxes_ws, hot_W, hot_thr, hot_cs, hotcnt);
  class_kernel<<<(NREC_ALL * 20 + 255) / 256, 256, 0, stream>>>(
      p0, p1, p2, hot_W, hot_thr, hot_cs, hotcnt, cand_keys, cand_cnt);
  nms_kernel<<<BATCH * NCLS, 64, 0, stream>>>(cand_keys, cand_cnt, boxes_ws,
                                              img_keys, img_cnt);
  final_kernel<<<BATCH, 1024, 0, stream>>>(img_keys, img_cnt, boxes_ws, (float*)d_out);
}

// Round 16
// 130.300 us; speedup vs baseline: 1.5758x; 1.5758x over previous
//
#include <hip/hip_runtime.h>
#include <stdint.h>

#define NCLS 80
#define MAXB 150
#define BATCH 16
#define NANCH 25200
#define SEGS 4       // candidate-list segments per (image,class) (atomic spread)
#define SEGCAP 512   // per-segment cap; mean fill ~150 -> ~10 sigma margin
#define CAP2 12000   // hard bound: 80 classes * 150 kept max
#define NBINS 411    // score hi-bits (0x3F666666,0x3F800000] -> bins 0..410
#define SELCAP 2048
#define WSEL 256     // nms per-wave compact capacity (expected ~155)
#define NREC_ALL 403200  // total records across levels/images (1575 blocks x 256)
#define CPAD 16          // counters padded to one per 64B line (atomic contention fix)

typedef unsigned long long u64;
typedef unsigned int u32;
typedef float f4 __attribute__((ext_vector_type(4)));
typedef f4 f4u __attribute__((aligned(4)));  // 4B-aligned vector load

__device__ __forceinline__ float sigm(float x) { return 1.0f / (1.0f + expf(-x)); }

// reference IoU, exact op order: inter / ((area_row + area_col) - inter + 1e-9)
__device__ __forceinline__ float iou_ref(float4 rb_, float ra, float4 cb, float ca) {
  float ltx = fmaxf(rb_.x, cb.x);
  float lty = fmaxf(rb_.y, cb.y);
  float rbx = fminf(rb_.z, cb.z);
  float rby = fminf(rb_.w, cb.w);
  float iw = fmaxf(rbx - ltx, 0.f);
  float ih = fmaxf(rby - lty, 0.f);
  float inter = iw * ih;
  return inter / (ra + ca - inter + 1e-9f);
}

// -- Pass 1 (fused, block-compacted): 256 records/block ------------------------
// Phase 1: thread/record; hot (cs>0.9, ~19%) -> box write + (W,thr,cs) to LDS
//          list via LDS atomic (no global counter -> no line serialization).
// Phase 2: dense sweep of the LDS hot list, 20 lanes per 320B row (coalesced),
//          thr pre-filter + exact test + segmented padded-atomic appends.
__global__ __launch_bounds__(256) void decode_kernel(
    const float* __restrict__ p0, const float* __restrict__ p1,
    const float* __restrict__ p2, float* __restrict__ boxes_ws,
    u64* __restrict__ cand_keys, int* __restrict__ cand_cnt) {
  __shared__ int hcnt;
  __shared__ u32 hW[256];
  __shared__ float hthr[256];
  __shared__ float hcs[256];
  int tid = threadIdx.x;
  if (tid == 0) hcnt = 0;
  __syncthreads();
  int W = blockIdx.x * 256 + tid;  // < 403200 always (grid = 1575 blocks)
  int lvl, b, r;
  if (W < 19200) { lvl = 0; b = W / 1200; r = W - b * 1200; }
  else if (W < 96000) { int V = W - 19200; lvl = 1; b = V / 4800; r = V - b * 4800; }
  else { int V = W - 96000; lvl = 2; b = V / 19200; r = V - b * 19200; }
  const int gtab[3] = {20, 40, 80};
  const float rtab[3] = {32.f, 16.f, 8.f};
  const int nbt[3] = {0, 1200, 6000};
  const float awt[3][3] = {{116.f, 156.f, 373.f}, {30.f, 62.f, 59.f}, {10.f, 16.f, 33.f}};
  const float aht[3][3] = {{90.f, 198.f, 326.f}, {61.f, 45.f, 119.f}, {13.f, 30.f, 23.f}};
  const float* fm = (lvl == 0) ? p0 : ((lvl == 1) ? p1 : p2);
  int g = gtab[lvl];
  const float* p = fm + ((size_t)b * (g * g * 3) + r) * 85;
  float tc = p[4];
  float cs = sigm(tc);  // score<=cs in fp32 -> cs>0.9 is a lossless gate
  if (cs > 0.9f) {
    f4 h = *(const f4u*)p;  // tx,ty,tw,th
    int cell = r / 3, a = r - 3 * cell;
    int yy = cell / g, xx = cell - yy * g;
    float ratio = rtab[lvl];
    float cx = (sigm(h.x) + (float)xx) * ratio;
    float cy = (sigm(h.y) + (float)yy) * ratio;
    float w = expf(h.z) * awt[lvl][a];
    float hh = expf(h.w) * aht[lvl][a];
    int n = nbt[lvl] + r;
    reinterpret_cast<float4*>(boxes_ws)[(size_t)b * NANCH + n] = make_float4(
        cx - w * 0.5f, cy - hh * 0.5f, cx + w * 0.5f, cy + hh * 0.5f);
    // conservative logit threshold: val <= thr ==> fl(cs*sigm(val)) <= 0.9f;
    // margin dominates all fp32 error terms; borderline FPs re-tested exactly.
    float t = 0.9f / cs;
    float ratio2 = t / (1.0f - t);
    float thr = logf(ratio2) - (1e-3f + 4e-7f * ratio2);
    int pos = atomicAdd(&hcnt, 1);  // LDS atomic: per-block, nanoseconds
    hW[pos] = (u32)W;
    hthr[pos] = thr;
    hcs[pos] = cs;
  }
  __syncthreads();
  int H = hcnt;  // ~49 expected
  // ---- phase 2: 240 threads = 12 records x 20 slots, dense hot sweep ----
  int idx = tid / 20, slot = tid - idx * 20;
  if (tid < 240) {
    for (int base = 0; base < H; base += 12) {
      int e = base + idx;
      if (e < H) {
        u32 Wr = hW[e];
        float thr = hthr[e];
        float cs = hcs[e];
        int lv2, b2, r2;
        const float* fm2;
        if (Wr < 19200u) { lv2 = 0; b2 = Wr / 1200u; r2 = Wr - b2 * 1200u; fm2 = p0; }
        else if (Wr < 96000u) { u32 V = Wr - 19200u; lv2 = 1; b2 = V / 4800u; r2 = V - b2 * 4800u; fm2 = p1; }
        else { u32 V = Wr - 96000u; lv2 = 2; b2 = V / 19200u; r2 = V - b2 * 19200u; fm2 = p2; }
        const int lbase[3] = {0, 19200, 96000};
        const float* pr = fm2 + (size_t)(Wr - (u32)lbase[lv2]) * 85;
        f4 v = *(const f4u*)(pr + 5 + 4 * slot);  // 16B class logits, coalesced/row
        u32 n = (u32)nbt[lv2] + (u32)r2;
        u32 nkey = 0xFFFFFFFFu - n;
        int seg = (int)(Wr & (SEGS - 1));
#pragma unroll
        for (int k = 0; k < 4; ++k) {
          if (v[k] > thr) {  // lossless pre-filter (thr conservative)
            float s = cs * sigm(v[k]);  // exact reference expression
            if (s > 0.9f) {
              int c = 4 * slot + k;
              int bc = b2 * NCLS + c;
              int pos = atomicAdd(&cand_cnt[(bc * SEGS + seg) * CPAD], 1);
              if (pos < SEGCAP)  // high = score bits, low = ~anchor
                cand_keys[((size_t)bc * SEGS + seg) * SEGCAP + pos] =
                    ((u64)__float_as_uint(s) << 32) | nkey;
            }
          }
        }
      }
    }
  }
}

// ------- Pass 2: one WAVE per (image,class): select top-150 + bitmask NMS -------
// Zero __syncthreads; serial NMS scan is register-only (no cross-lane ops).
__global__ __launch_bounds__(64) void nms_kernel(
    const u64* __restrict__ cand_keys, const int* __restrict__ cand_cnt,
    const float* __restrict__ boxes_ws,
    u64* __restrict__ img_keys, int* __restrict__ img_cnt) {
  __shared__ u64 sk[SEGS * SEGCAP];  // 16 KB staged keys
  __shared__ u64 sel[WSEL + 8];      // compact buffer (+pad)
  __shared__ u64 slot[MAXB];         // top-150 keys by exact rank
  __shared__ float4 sbox[MAXB];
  __shared__ float sarea[MAXB];
  __shared__ u64 adjm[MAXB][3];      // adjacency rows: 192-bit masks
  __shared__ u32 hist[NBINS];
  int bc = blockIdx.x;
  int b = bc / NCLS, c = bc - b * NCLS;
  int lane = threadIdx.x;
  u64 ltm = (1ull << lane) - 1;
  int cnt[SEGS];
  int count = 0;
#pragma unroll
  for (int s = 0; s < SEGS; ++s) {
    int v = cand_cnt[(bc * SEGS + s) * CPAD];
    cnt[s] = (v > SEGCAP) ? SEGCAP : v;
    count += cnt[s];
  }
  const u64* seg_base = cand_keys + (size_t)bc * SEGS * SEGCAP;
  for (int i = lane; i < NBINS; i += 64) hist[i] = 0;
  for (int i = lane; i < MAXB; i += 64) slot[i] = 0;
  // ---- stage keys to LDS + histogram in ONE pass ----
  {
    int off = 0;
#pragma unroll
    for (int s = 0; s < SEGS; ++s) {
      for (int i = lane; i < cnt[s]; i += 64) {
        u64 k = seg_base[s * SEGCAP + i];
        sk[off + i] = k;
        atomicAdd(&hist[((u32)(k >> 32) - 0x3F666000u) >> 12], 1u);
      }
      off += cnt[s];
    }
  }
  __threadfence_block();
  // ---- wave-parallel suffix-scan threshold: lane owns 7-bin chunk ----
  int target = (count < MAXB) ? count : MAXB;
  u32 bsum[7];
  u32 csum = 0;
  int chunk = lane * 7;  // 64*7 = 448 >= NBINS
#pragma unroll
  for (int m = 0; m < 7; ++m) {
    int j = chunk + m;
    u32 hv = (j < NBINS) ? hist[j] : 0u;
    bsum[m] = hv;
    csum += hv;
  }
  u32 S = csum;  // inclusive suffix sum over lanes
#pragma unroll
  for (int off = 1; off < 64; off <<= 1) {
    u32 o = __shfl_down(S, off);
    if (lane + off < 64) S += o;
  }
  u32 Snext = S - csum;
  bool win = (S >= (u32)target) && (Snext < (u32)target);  // unique lane (target>=1)
  u64 wmask = __ballot(win);
  int T = NBINS;
  u32 Cge = 0;
  if (wmask) {
    int Tc = 0;
    u32 Cc = 0;
    if (win) {
      u32 acc = Snext;
#pragma unroll
      for (int m = 6; m >= 0; --m) {
        acc += bsum[m];
        if (acc >= (u32)target) { Tc = chunk + m; Cc = acc; break; }
      }
    }
    int wl = __ffsll(wmask) - 1;
    T = __shfl(Tc, wl);
    Cge = __shfl(Cc, wl);
  }
  // ---- select top-`target` keys into slot[rank] ----
  if (Cge <= WSEL) {
    int C = 0;  // compact bins >= T via ballot offsets; C == Cge
    for (int i0 = 0; i0 < count; i0 += 64) {
      int i = i0 + lane;
      bool in = false;
      u64 k = 0;
      if (i < count) {
        k = sk[i];
        in = (int)(((u32)(k >> 32) - 0x3F666000u) >> 12) >= T;
      }
      u64 m = __ballot(in);
      if (in) sel[C + (int)__popcll(m & ltm)] = k;
      C += (int)__popcll(m);
    }
    int C8 = (C + 7) & ~7;
    for (int j = C + lane; j < C8; j += 64) sel[j] = 0;  // pad: 0 never outranks
    __threadfence_block();
    for (int i = lane; i < C; i += 64) {  // rank-select, broadcast reads, 8-deep
      u64 k = sel[i];
      int rank = 0;
      for (int j = 0; j < C8; j += 8) {
        rank += (int)(sel[j] > k) + (int)(sel[j + 1] > k) + (int)(sel[j + 2] > k) +
                (int)(sel[j + 3] > k) + (int)(sel[j + 4] > k) + (int)(sel[j + 5] > k) +
                (int)(sel[j + 6] > k) + (int)(sel[j + 7] > k);
      }
      if (rank < MAXB) slot[rank] = k;
    }
  } else {
    // fallback (pathological bin concentration; never taken on this data)
    int C8 = (count + 7) & ~7;  // <= 2048 (sk capacity)
    for (int j = count + lane; j < C8; j += 64) sk[j] = 0;
    __threadfence_block();
    for (int i = lane; i < count; i += 64) {
      u64 k = sk[i];
      int rank = 0;
      for (int j = 0; j < C8; j += 8) {
        rank += (int)(sk[j] > k) + (int)(sk[j + 1] > k) + (int)(sk[j + 2] > k) +
                (int)(sk[j + 3] > k) + (int)(sk[j + 4] > k) + (int)(sk[j + 5] > k) +
                (int)(sk[j + 6] > k) + (int)(sk[j + 7] > k);
      }
      if (rank < MAXB) slot[rank] = k;
    }
  }
  __threadfence_block();
  // ---- boxes: registers for my 3 rows + LDS copy for broadcast columns ----
  float4 rb0, rb1, rb2;
  float ra0 = 0.f, ra1 = 0.f, ra2 = 0.f;
  rb0 = rb1 = rb2 = make_float4(0.f, 0.f, 0.f, 0.f);
#pragma unroll
  for (int w = 0; w < 3; ++w) {
    int j = lane + 64 * w;
    float4 bx = make_float4(0.f, 0.f, 0.f, 0.f);
    float ar = 0.f;
    if (j < MAXB && slot[j] != 0) {
      int n = (int)(0xFFFFFFFFu - (u32)(slot[j] & 0xFFFFFFFFu));
      bx = reinterpret_cast<const float4*>(boxes_ws)[(size_t)b * NANCH + n];
      ar = (bx.z - bx.x) * (bx.w - bx.y);
    }
    if (j < MAXB) { sbox[j] = bx; sarea[j] = ar; }
    if (w == 0) { rb0 = bx; ra0 = ar; }
    else if (w == 1) { rb1 = bx; ra1 = ar; }
    else { rb2 = bx; ra2 = ar; }
  }
  u64 valid0 = __ballot(slot[lane] != 0);
  u64 valid1 = __ballot(lane + 64 < MAXB && slot[lane + 64] != 0);
  u64 valid2 = __ballot(lane + 128 < MAXB && slot[lane + 128] != 0);
  __threadfence_block();
  // ---- adjacency build: row r mask = {bits j : j > r, iou(r,j) > 0.1} ----
  int jb0 = (target < 64) ? target : 64;
  int jb1 = (target < 128) ? target : 128;
  int jb2 = target;
  u64 r0m0 = 0, r0m1 = 0, r0m2 = 0, r1m1 = 0, r1m2 = 0, r2m2 = 0;
  bool rv0 = (valid0 >> lane) & 1, rv1 = (valid1 >> lane) & 1,
       rv2 = (valid2 >> lane) & 1;
  if (rv0) {
    u64 bit = 1ull;
    for (int j = 0; j < jb0; ++j, bit <<= 1)
      if (j > lane && iou_ref(rb0, ra0, sbox[j], sarea[j]) > 0.1f) r0m0 |= bit;
    bit = 1ull;
    for (int j = 64; j < jb1; ++j, bit <<= 1)
      if (iou_ref(rb0, ra0, sbox[j], sarea[j]) > 0.1f) r0m1 |= bit;
    bit = 1ull;
    for (int j = 128; j < jb2; ++j, bit <<= 1)
      if (iou_ref(rb0, ra0, sbox[j], sarea[j]) > 0.1f) r0m2 |= bit;
  }
  if (rv1) {
    u64 bit = 1ull;
    for (int j = 64; j < jb1; ++j, bit <<= 1)
      if (j > lane + 64 && iou_ref(rb1, ra1, sbox[j], sarea[j]) > 0.1f) r1m1 |= bit;
    bit = 1ull;
    for (int j = 128; j < jb2; ++j, bit <<= 1)
      if (iou_ref(rb1, ra1, sbox[j], sarea[j]) > 0.1f) r1m2 |= bit;
  }
  if (rv2) {
    u64 bit = 1ull;
    for (int j = 128; j < jb2; ++j, bit <<= 1)
      if (j > lane + 128 && iou_ref(rb2, ra2, sbox[j], sarea[j]) > 0.1f) r2m2 |= bit;
  }
  if (lane < MAXB) { adjm[lane][0] = r0m0; adjm[lane][1] = r0m1; adjm[lane][2] = r0m2; }
  if (lane + 64 < MAXB) { adjm[lane + 64][0] = 0; adjm[lane + 64][1] = r1m1; adjm[lane + 64][2] = r1m2; }
  if (lane + 128 < MAXB) { adjm[lane + 128][0] = 0; adjm[lane + 128][1] = 0; adjm[lane + 128][2] = r2m2; }
  __threadfence_block();
  // ---- serial greedy scan: register-only chain, identical in every lane ----
  u64 sup0 = 0, sup1 = 0, sup2 = 0;
  {
    u64 bit = 1ull;
    int e0 = (target < 64) ? target : 64;
    for (int i = 0; i < e0; ++i, bit <<= 1)
      if (valid0 & ~sup0 & bit) { sup0 |= adjm[i][0]; sup1 |= adjm[i][1]; sup2 |= adjm[i][2]; }
    bit = 1ull;
    int e1 = (target < 128) ? target - 64 : 64;
    for (int i = 0; i < e1; ++i, bit <<= 1)
      if (valid1 & ~sup1 & bit) { sup1 |= adjm[i + 64][1]; sup2 |= adjm[i + 64][2]; }
    bit = 1ull;
    int e2 = target - 128;
    for (int i = 0; i < e2; ++i, bit <<= 1)
      if (valid2 & ~sup2 & bit) { sup2 |= adjm[i + 128][2]; }
  }
  // ---- keep masks are uniform registers -> appends need no ballots ----
  u64 m0 = valid0 & ~sup0, m1 = valid1 & ~sup1, m2 = valid2 & ~sup2;
  int total = (int)(__popcll(m0) + __popcll(m1) + __popcll(m2));
  if (total > 0) {
    int base = 0;
    if (lane == 0) base = atomicAdd(&img_cnt[b * CPAD], total);
    base = __shfl(base, 0);
    int off0 = (int)__popcll(m0 & ltm);
    int off1 = (int)(__popcll(m0) + __popcll(m1 & ltm));
    int off2 = (int)(__popcll(m0) + __popcll(m1) + __popcll(m2 & ltm));
#pragma unroll
    for (int w = 0; w < 3; ++w) {
      u64 mw = (w == 0) ? m0 : ((w == 1) ? m1 : m2);
      if ((mw >> lane) & 1) {
        int j = lane + 64 * w;  // j == rank == top_k position
        u64 k = slot[j];
        u32 e = (u32)(c * MAXB + j);
        u32 anchor = (u32)(0xFFFFFFFFu - (u32)(k & 0xFFFFFFFFu));
        int pos = base + ((w == 0) ? off0 : ((w == 1) ? off1 : off2));
        // key = [score:32][(0x3FFF - e):14][anchor:15]  (unique per entry)
        img_keys[(size_t)b * CAP2 + pos] =
            ((k >> 32) << 32) | ((u64)(0x3FFFu - e) << 15) | anchor;
      }
    }
  }
}

// ---------------- Pass 3: per-image top-150 via exact histogram select ----------
__global__ __launch_bounds__(1024) void final_kernel(
    const u64* __restrict__ img_keys, const int* __restrict__ img_cnt,
    const float* __restrict__ boxes_ws, float* __restrict__ out) {
  __shared__ u32 hist[NBINS];
  __shared__ u64 sel[SELCAP];   // 16 KB
  __shared__ u64 slot[MAXB];
  __shared__ int sT, sCge, nsel;
  int b = blockIdx.x, tid = threadIdx.x;
  int L = img_cnt[b * CPAD];
  if (L > CAP2) L = CAP2;
  const u64* src = img_keys + (size_t)b * CAP2;
  for (int i = tid; i < NBINS; i += 1024) hist[i] = 0;
  if (tid < MAXB) slot[tid] = 0;
  if (tid == 0) nsel = 0;
  __syncthreads();
  for (int i = tid; i < L; i += 1024) {
    u32 hi = (u32)(src[i] >> 32);
    atomicAdd(&hist[(hi - 0x3F666000u) >> 12], 1u);
  }
  __syncthreads();
  if (tid < 64) {  // wave-parallel suffix-scan threshold
    int lane = tid;
    int target = (L < MAXB) ? L : MAXB;
    u32 bsum[7];
    u32 csum = 0;
    int chunk = lane * 7;
#pragma unroll
    for (int m = 0; m < 7; ++m) {
      int j = chunk + m;
      u32 hv = (j < NBINS) ? hist[j] : 0u;
      bsum[m] = hv;
      csum += hv;
    }
    u32 S = csum;
#pragma unroll
    for (int off = 1; off < 64; off <<= 1) {
      u32 o = __shfl_down(S, off);
      if (lane + off < 64) S += o;
    }
    u32 Snext = S - csum;
    bool win = (S >= (u32)target) && (Snext < (u32)target);
    u64 wmask = __ballot(win);
    int T = NBINS;
    u32 Cge = 0;
    if (wmask) {
      int Tc = 0;
      u32 Cc = 0;
      if (win) {
        u32 acc = Snext;
#pragma unroll
        for (int m = 6; m >= 0; --m) {
          acc += bsum[m];
          if (acc >= (u32)target) { Tc = chunk + m; Cc = acc; break; }
        }
      }
      int wl = __ffsll(wmask) - 1;
      T = __shfl(Tc, wl);
      Cge = __shfl(Cc, wl);
    }
    if (lane == 0) { sT = T; sCge = (int)Cge; }
  }
  __syncthreads();
  int T = sT, cge = sCge;
  float* ob = out;                      // [B][150][4]
  float* osc = out + BATCH * MAXB * 4;  // [B][150]
  float* olb = out + BATCH * MAXB * 5;  // [B][150] labels (as float)
  if (cge <= SELCAP) {
    for (int i = tid; i < L; i += 1024) {
      u64 k = src[i];
      if ((int)(((u32)(k >> 32) - 0x3F666000u) >> 12) >= T) {
        int pos = atomicAdd(&nsel, 1);
        sel[pos] = k;
      }
    }
    __syncthreads();
    int C = nsel;
    for (int i = tid; i < C; i += 1024) {
      u64 k = sel[i];
      int rank = 0;
      for (int j = 0; j < C; ++j) rank += (sel[j] > k) ? 1 : 0;  // LDS broadcast
      if (rank < MAXB) slot[rank] = k;
    }
    __syncthreads();
  } else {
    for (int i = tid; i < L; i += 1024) {
      u64 k = src[i];
      int rank = 0;
      for (int j = 0; j < L; ++j) rank += (src[j] > k) ? 1 : 0;
      if (rank < MAXB) slot[rank] = k;
    }
    __syncthreads();
  }
  if (tid < MAXB) {
    u64 k = slot[tid];
    float* q = ob + ((size_t)b * MAXB + tid) * 4;
    if (k) {
      u32 e = 0x3FFFu - (u32)((k >> 15) & 0x3FFFu);
      int c = (int)(e / MAXB);
      int anchor = (int)(k & 0x7FFFu);
      float4 bx = reinterpret_cast<const float4*>(boxes_ws)[(size_t)b * NANCH + anchor];
      q[0] = bx.x; q[1] = bx.y; q[2] = bx.z; q[3] = bx.w;
      osc[(size_t)b * MAXB + tid] = __uint_as_float((u32)(k >> 32));
      olb[(size_t)b * MAXB + tid] = (float)c;
    } else {
      q[0] = q[1] = q[2] = q[3] = -1.f;
      osc[(size_t)b * MAXB + tid] = -1.f;
      olb[(size_t)b * MAXB + tid] = -1.f;
    }
  }
}

extern "C" void kernel_launch(void* const* d_in, const int* in_sizes, int n_in,
                              void* d_out, int out_size, void* d_ws, size_t ws_size,
                              hipStream_t stream) {
  (void)in_sizes; (void)n_in; (void)out_size; (void)ws_size;
  const float* p0 = (const float*)d_in[0];  // [16,20,20,255] anchors[6:9]
  const float* p1 = (const float*)d_in[1];  // [16,40,40,255] anchors[3:6]
  const float* p2 = (const float*)d_in[2];  // [16,80,80,255] anchors[0:3]
  char* ws = (char*)d_ws;
  float* boxes_ws = (float*)ws;              // 16*25200*16 B          -> 6,451,200
  int* cand_cnt = (int*)(ws + 6451200);      // 1280*4*16 i32 (padded) -> 6,778,880
  int* img_cnt = (int*)(ws + 6778880);       // 16*16 i32 (padded)     -> 6,779,904
  u64* cand_keys = (u64*)(ws + 6779904);     // 1280*4*512 u64         -> 27,751,424
  u64* img_keys = (u64*)(ws + 27751424);     // 16*12000 u64           -> 29,287,424

  hipMemsetAsync(cand_cnt, 0, (NCLS * BATCH * SEGS + BATCH) * CPAD * sizeof(int),
                 stream);

  decode_kernel<<<NREC_ALL / 256, 256, 0, stream>>>(
      p0, p1, p2, boxes_ws, cand_keys, cand_cnt);
  nms_kernel<<<BATCH * NCLS, 64, 0, stream>>>(cand_keys, cand_cnt, boxes_ws,
                                              img_keys, img_cnt);
  final_kernel<<<BATCH, 1024, 0, stream>>>(img_keys, img_cnt, boxes_ws, (float*)d_out);
}